// Round 3
// baseline (9488.715 us; speedup 1.0000x reference)
//
#include <hip/hip_runtime.h>

#define BB 256
#define SEQ 512
#define IDIM 32
#define HDIM 128
#define ODIM 64
#define NSUB 8

typedef float v2f __attribute__((ext_vector_type(2)));

// quad_perm [1,2,3,0]: new[u] = old[(u+1)&3]  (ctrl = 1 + 2*4 + 3*16 + 0*64 = 0x39)
__device__ __forceinline__ v2f quad_rot1(v2f v) {
    v2f r;
    r.x = __int_as_float(__builtin_amdgcn_mov_dpp(__float_as_int(v.x), 0x39, 0xF, 0xF, false));
    r.y = __int_as_float(__builtin_amdgcn_mov_dpp(__float_as_int(v.y), 0x39, 0xF, 0xF, false));
    return r;
}

// One block per batch element; 256 threads = 4 waves.
// Lane map: w = tid>>6, l = tid&63, half = l>>5, j = 32*w + (l&31), u = l&3.
// Each thread owns output row j, k-half [64*half, 64*half+64).
// Per stage: quad-shared LDS read (each lane 1 float4 chunk per round, 4 rounds),
// chunks circulate in-quad via DPP; W_h pre-permuted to match rotation schedule.
__global__ __launch_bounds__(256) void lnn_recur(
    const float* __restrict__ x,
    const float* __restrict__ Wx,
    const float* __restrict__ Wh,
    const float* __restrict__ bias,
    const float* __restrict__ tau,
    float* __restrict__ hs)
{
    __shared__ float abuf[2][HDIM];
    const int b    = blockIdx.x;
    const int tid  = threadIdx.x;
    const int w    = tid >> 6;
    const int l    = tid & 63;
    const int u    = l & 3;
    const int half = l >> 5;
    const int j    = 32 * w + (l & 31);
    const bool wr  = (l < 32);   // half==0 lanes write the shared vector

    // W_h row-half, rotation-schedule order: wq2[r][s] = chunk (4r + ((u+s)&3))
    v2f wq2[4][4][2];
    #pragma unroll
    for (int r = 0; r < 4; ++r) {
        #pragma unroll
        for (int s = 0; s < 4; ++s) {
            int c = 4 * r + ((u + s) & 3);
            float4 wv = *reinterpret_cast<const float4*>(Wh + j * HDIM + half * 64 + 4 * c);
            wq2[r][s][0] = v2f{wv.x, wv.y};
            wq2[r][s][1] = v2f{wv.z, wv.w};
        }
    }
    // W_x row-half (16 floats)
    v2f wx2[8];
    {
        const float4* wp = reinterpret_cast<const float4*>(Wx + j * IDIM + half * 16);
        #pragma unroll
        for (int m = 0; m < 4; ++m) {
            float4 v = wp[m];
            wx2[2*m+0] = v2f{v.x, v.y};
            wx2[2*m+1] = v2f{v.z, v.w};
        }
    }
    const float bj   = bias[j];
    const float itau = 1.0f / (fabsf(tau[j]) + 0.001f);
    const float DT   = 1.0f / (float)NSUB;
    const float dti  = DT * itau;
    const float K2E  = 2.885390081777927f;  // 2*log2(e)

    float h  = 0.0f;
    int  par = 0;

    #pragma unroll 1
    for (int t = 0; t < SEQ; ++t) {
        float cbase;
        {
            const float4* xp4 = reinterpret_cast<const float4*>(x + ((size_t)b * SEQ + t) * IDIM + half * 16);
            v2f p0 = v2f{0.f, 0.f}, p1 = v2f{0.f, 0.f};
            #pragma unroll
            for (int m = 0; m < 4; ++m) {
                float4 v = xp4[m];
                p0 += wx2[2*m+0] * v2f{v.x, v.y};
                p1 += wx2[2*m+1] * v2f{v.z, v.w};
            }
            v2f ps = p0 + p1;
            float px = ps.x + ps.y;
            px += __shfl_xor(px, 32);
            cbase = px + bj;
        }

        #pragma unroll 1
        for (int s = 0; s < NSUB; ++s) {
            float m1, m2, m3, m4, m5, m6;

            // m = dt*k = dti * (tanh(cbase + Wh.a) - a)
            auto stage = [&](float a) -> float {
                if (wr) abuf[par][j] = a;
                __syncthreads();
                const float* ab = &abuf[par][half * 64 + 4 * u];
                // issue all 4 chunk reads up front (pipelined lgkmcnt)
                float4 va0 = *reinterpret_cast<const float4*>(ab + 0);
                float4 va1 = *reinterpret_cast<const float4*>(ab + 16);
                float4 va2 = *reinterpret_cast<const float4*>(ab + 32);
                float4 va3 = *reinterpret_cast<const float4*>(ab + 48);
                v2f p0 = v2f{0.f, 0.f}, p1 = v2f{0.f, 0.f};
                v2f p2 = v2f{0.f, 0.f}, p3 = v2f{0.f, 0.f};

                {   // round 0
                    v2f lo = v2f{va0.x, va0.y}, hi = v2f{va0.z, va0.w};
                    p0 += lo * wq2[0][0][0]; p1 += hi * wq2[0][0][1];
                    lo = quad_rot1(lo); hi = quad_rot1(hi);
                    p0 += lo * wq2[0][1][0]; p1 += hi * wq2[0][1][1];
                    lo = quad_rot1(lo); hi = quad_rot1(hi);
                    p0 += lo * wq2[0][2][0]; p1 += hi * wq2[0][2][1];
                    lo = quad_rot1(lo); hi = quad_rot1(hi);
                    p0 += lo * wq2[0][3][0]; p1 += hi * wq2[0][3][1];
                }
                {   // round 1
                    v2f lo = v2f{va1.x, va1.y}, hi = v2f{va1.z, va1.w};
                    p2 += lo * wq2[1][0][0]; p3 += hi * wq2[1][0][1];
                    lo = quad_rot1(lo); hi = quad_rot1(hi);
                    p2 += lo * wq2[1][1][0]; p3 += hi * wq2[1][1][1];
                    lo = quad_rot1(lo); hi = quad_rot1(hi);
                    p2 += lo * wq2[1][2][0]; p3 += hi * wq2[1][2][1];
                    lo = quad_rot1(lo); hi = quad_rot1(hi);
                    p2 += lo * wq2[1][3][0]; p3 += hi * wq2[1][3][1];
                }
                {   // round 2
                    v2f lo = v2f{va2.x, va2.y}, hi = v2f{va2.z, va2.w};
                    p0 += lo * wq2[2][0][0]; p1 += hi * wq2[2][0][1];
                    lo = quad_rot1(lo); hi = quad_rot1(hi);
                    p0 += lo * wq2[2][1][0]; p1 += hi * wq2[2][1][1];
                    lo = quad_rot1(lo); hi = quad_rot1(hi);
                    p0 += lo * wq2[2][2][0]; p1 += hi * wq2[2][2][1];
                    lo = quad_rot1(lo); hi = quad_rot1(hi);
                    p0 += lo * wq2[2][3][0]; p1 += hi * wq2[2][3][1];
                }
                {   // round 3
                    v2f lo = v2f{va3.x, va3.y}, hi = v2f{va3.z, va3.w};
                    p2 += lo * wq2[3][0][0]; p3 += hi * wq2[3][0][1];
                    lo = quad_rot1(lo); hi = quad_rot1(hi);
                    p2 += lo * wq2[3][1][0]; p3 += hi * wq2[3][1][1];
                    lo = quad_rot1(lo); hi = quad_rot1(hi);
                    p2 += lo * wq2[3][2][0]; p3 += hi * wq2[3][2][1];
                    lo = quad_rot1(lo); hi = quad_rot1(hi);
                    p2 += lo * wq2[3][3][0]; p3 += hi * wq2[3][3][1];
                }

                v2f pt = (p0 + p1) + (p2 + p3);
                float dot = pt.x + pt.y;
                dot += __shfl_xor(dot, 32);      // combine k-halves (partner lane l^32)
                par ^= 1;
                float z  = cbase + dot;
                float e  = exp2f(z * K2E);
                float th = 1.0f - 2.0f * __builtin_amdgcn_rcpf(1.0f + e);
                return dti * (th - a);
            };

            m1 = stage(h);
            m2 = stage(h + 0.2f * m1);
            m3 = stage(h + (0.075f * m1 + 0.225f * m2));
            m4 = stage(h + ((44.0f/45.0f) * m1 - (56.0f/15.0f) * m2) + (32.0f/9.0f) * m3);
            m5 = stage(h + ((19372.0f/6561.0f) * m1 - (25360.0f/2187.0f) * m2)
                         + ((64448.0f/6561.0f) * m3 - (212.0f/729.0f) * m4));
            m6 = stage(h + ((9017.0f/3168.0f) * m1 - (355.0f/33.0f) * m2)
                         + ((46732.0f/5247.0f) * m3 + (49.0f/176.0f) * m4)
                         - (5103.0f/18656.0f) * m5);
            h = h + (((35.0f/384.0f) * m1 + (500.0f/1113.0f) * m3)
                   + ((125.0f/192.0f) * m4 - (2187.0f/6784.0f) * m5))
                  + (11.0f/84.0f) * m6;
        }

        if (wr) hs[((size_t)b * SEQ + t) * HDIM + j] = h;
    }
}

// outs[bt][o] = hs[bt] . Wout_row_o + bout[o]
__global__ __launch_bounds__(256) void lnn_out(
    const float* __restrict__ hs,
    const float* __restrict__ Wout,
    const float* __restrict__ bout,
    float* __restrict__ outs)
{
    __shared__ float wt[HDIM][ODIM + 1];
    const int tid = threadIdx.x;
    for (int i = tid; i < HDIM * ODIM; i += 256) {
        int o = i >> 7;
        int k = i & 127;
        wt[k][o] = Wout[i];
    }
    __syncthreads();

    const int o = tid & 63;
    const int r = tid >> 6;
    const float bo = bout[o];
    const int nbt = BB * SEQ;

    for (int bt = blockIdx.x * 4 + r; bt < nbt; bt += gridDim.x * 4) {
        const float4* hp = reinterpret_cast<const float4*>(hs + (size_t)bt * HDIM);
        float acc0 = bo, acc1 = 0.f, acc2 = 0.f, acc3 = 0.f;
        #pragma unroll
        for (int kk = 0; kk < 32; ++kk) {
            float4 v = hp[kk];
            acc0 += v.x * wt[4*kk+0][o];
            acc1 += v.y * wt[4*kk+1][o];
            acc2 += v.z * wt[4*kk+2][o];
            acc3 += v.w * wt[4*kk+3][o];
        }
        outs[(size_t)bt * ODIM + o] = (acc0 + acc1) + (acc2 + acc3);
    }
}

extern "C" void kernel_launch(void* const* d_in, const int* in_sizes, int n_in,
                              void* d_out, int out_size, void* d_ws, size_t ws_size,
                              hipStream_t stream) {
    const float* x    = (const float*)d_in[0];
    const float* Wx   = (const float*)d_in[1];
    const float* Wh   = (const float*)d_in[2];
    const float* bias = (const float*)d_in[3];
    const float* tau  = (const float*)d_in[4];
    const float* Wout = (const float*)d_in[5];
    const float* bout = (const float*)d_in[6];

    float* outs = (float*)d_out;
    float* hs   = outs + (size_t)BB * SEQ * ODIM;

    lnn_recur<<<BB, 256, 0, stream>>>(x, Wx, Wh, bias, tau, hs);
    lnn_out<<<2048, 256, 0, stream>>>(hs, Wout, bout, outs);
}